// Round 2
// baseline (2442.852 us; speedup 1.0000x reference)
//
#include <hip/hip_runtime.h>
#include <hip/hip_bf16.h>
#include <math.h>

#define HH 112
#define WW_ 112
#define CC 96
#define NHH 3
#define WSZ 7
#define SHIFT_ 3
#define NTOK 49
#define HDIM 32
#define WTOT 8192          // total windows = B * 16 * 16
#define MTOT 401408        // WTOT * NTOK

typedef __hip_bfloat16 bf16;
typedef __attribute__((ext_vector_type(8))) short short8;
typedef __attribute__((ext_vector_type(4))) float floatx4;

static __device__ __forceinline__ float bits2f(short s) {
  return __uint_as_float(((unsigned)(unsigned short)s) << 16);
}
static __device__ __forceinline__ short f2bits(float v) {
  bf16 h = __float2bfloat16(v);
  short s;
  __builtin_memcpy(&s, &h, 2);
  return s;
}
static __device__ __forceinline__ float bf2f(bf16 v) { return __bfloat162float(v); }
static __device__ __forceinline__ bf16 f2bf(float v) { return __float2bfloat16(v); }

// IO abstraction: the harness's float tensors are either f32 or bf16; we
// detect at runtime and run the matching templated pipeline.
template <typename T> struct IO;
template <> struct IO<float> {
  static constexpr int kind = 1;
  static __device__ __forceinline__ float ld(const float* p, long i) { return p[i]; }
  static __device__ __forceinline__ void st(float* p, long i, float v) { p[i] = v; }
  static __device__ __forceinline__ short8 frag(const float* p) {
    short8 r;
#pragma unroll
    for (int j = 0; j < 8; ++j) r[j] = f2bits(p[j]);
    return r;
  }
};
template <> struct IO<bf16> {
  static constexpr int kind = 0;
  static __device__ __forceinline__ float ld(const bf16* p, long i) { return bf2f(p[i]); }
  static __device__ __forceinline__ void st(bf16* p, long i, float v) { p[i] = f2bf(v); }
  static __device__ __forceinline__ short8 frag(const bf16* p) { return *(const short8*)p; }
};

// ---------------------------------------------------------------------------
// dtype detection: read first 8192 uint16 of x. If the buffer is f32, even
// elements are mantissa bits -> ~25% decode to bf16 with |v| >= 128. If it's
// bf16 N(0,1), none do. flag: 1 = f32, 0 = bf16.
// ---------------------------------------------------------------------------
__global__ void detect_kernel(const unsigned short* __restrict__ x, int* flag) {
  __shared__ int tot;
  if (threadIdx.x == 0) tot = 0;
  __syncthreads();
  int bad = 0;
  for (int i = threadIdx.x; i < 8192; i += 256) {
    int e = (x[i] >> 7) & 0xFF;
    if (e >= 0x86) bad++;  // |value| >= 128 (or inf/nan)
  }
  atomicAdd(&tot, bad);
  __syncthreads();
  if (threadIdx.x == 0) *flag = (tot > 64) ? 1 : 0;
}

// ---------------------------------------------------------------------------
// LN: one wave per token. GATHER=1 fuses cyclic shift + window partition.
// Output always bf16 (internal format).
// ---------------------------------------------------------------------------
template <typename T, int GATHER>
__global__ __launch_bounds__(256) void ln_kernel(
    const int* __restrict__ flag, const T* __restrict__ x,
    const T* __restrict__ g, const T* __restrict__ b, bf16* __restrict__ out) {
  if (*flag != IO<T>::kind) return;
  int wid = threadIdx.x >> 6;
  int lane = threadIdx.x & 63;
  long t = (long)blockIdx.x * 4 + wid;  // token index in OUTPUT order
  const T* src;
  if (GATHER) {
    int win = (int)(t / NTOK);
    int n = (int)(t - (long)win * NTOK);
    int bq = win >> 8, wi = win & 255;
    int wh = wi >> 4, ww = wi & 15;
    int i = n / WSZ, j = n - (n / WSZ) * WSZ;
    int hs = wh * WSZ + i + SHIFT_; if (hs >= HH) hs -= HH;
    int ws = ww * WSZ + j + SHIFT_; if (ws >= WW_) ws -= WW_;
    src = x + ((long)bq * (HH * WW_) + (long)hs * WW_ + ws) * CC;
  } else {
    src = x + t * CC;
  }
  float v0 = IO<T>::ld(src, lane);
  float v1 = (lane < 32) ? IO<T>::ld(src, 64 + lane) : 0.f;
  float s = v0 + v1;
#pragma unroll
  for (int m = 32; m; m >>= 1) s += __shfl_xor(s, m, 64);
  float mean = s * (1.f / CC);
  float d0 = v0 - mean;
  float d1 = v1 - mean;
  float sq = d0 * d0 + ((lane < 32) ? d1 * d1 : 0.f);
#pragma unroll
  for (int m = 32; m; m >>= 1) sq += __shfl_xor(sq, m, 64);
  float rstd = rsqrtf(sq * (1.f / CC) + 1e-5f);
  bf16* dst = out + t * CC;
  dst[lane] = f2bf(d0 * rstd * IO<T>::ld(g, lane) + IO<T>::ld(b, lane));
  if (lane < 32)
    dst[64 + lane] =
        f2bf(d1 * rstd * IO<T>::ld(g, 64 + lane) + IO<T>::ld(b, 64 + lane));
}

// ---------------------------------------------------------------------------
// Fused QKV GEMM + window attention. One block per window (49 tokens, padded
// to 64 rows). 4 waves compute qkv (64x288) into LDS via MFMA; then waves
// 0..2 each run one head's softmax-attention from LDS. attn_out is written
// IN-PLACE over xw (each block only rereads its own rows; pad-row reads of a
// neighbor window's rows are discarded, so the cross-block race is benign).
// ---------------------------------------------------------------------------
template <typename T>
__global__ __launch_bounds__(256) void qkv_attn_kernel(
    const int* __restrict__ flag, const bf16* __restrict__ xw,
    const T* __restrict__ qkv_w, const T* __restrict__ qkv_b,
    const T* __restrict__ mask, const int* __restrict__ rel_index,
    const T* __restrict__ bias_table, bf16* __restrict__ attn_out) {
  if (*flag != IO<T>::kind) return;
  __shared__ short qk[64 * 288];  // 36864 B: q|k|v concat per row
  __shared__ float bq[288];
  int win = blockIdx.x;
  int wave = threadIdx.x >> 6;
  int lane = threadIdx.x & 63;
  int col = lane & 15;
  int kg = lane >> 4;
  for (int i = threadIdx.x; i < 288; i += 256) bq[i] = IO<T>::ld(qkv_b, i);
  long row = (long)win * NTOK + wave * 16 + col;
  if (row >= MTOT) row = MTOT - 1;  // pad rows: garbage-but-finite, discarded
  short8 af[3];
#pragma unroll
  for (int kc = 0; kc < 3; ++kc)
    af[kc] = *(const short8*)(xw + row * CC + kc * 32 + kg * 8);
  __syncthreads();
  for (int nc = 0; nc < 18; ++nc) {
    floatx4 acc = {0.f, 0.f, 0.f, 0.f};
#pragma unroll
    for (int kc = 0; kc < 3; ++kc) {
      short8 bf = IO<T>::frag(qkv_w + (long)(nc * 16 + col) * CC + kc * 32 + kg * 8);
      acc = __builtin_amdgcn_mfma_f32_16x16x32_bf16(af[kc], bf, acc, 0, 0, 0);
    }
    int cc = nc * 16 + col;
    float bb = bq[cc];
#pragma unroll
    for (int r = 0; r < 4; ++r)
      qk[(wave * 16 + kg * 4 + r) * 288 + cc] = f2bits(acc[r] + bb);
  }
  __syncthreads();
  int head = wave;
  if (head < NHH && lane < NTOK) {
    const float scale = 0.17677669529663687f;  // 1/sqrt(32)
    float q[HDIM];
    {
      const short* qp = qk + lane * 288 + head * HDIM;
#pragma unroll
      for (int jj = 0; jj < 4; ++jj) {
        short8 v8 = *(const short8*)(qp + jj * 8);
#pragma unroll
        for (int j = 0; j < 8; ++j) q[jj * 8 + j] = bits2f(v8[j]) * scale;
      }
    }
    const T* mrow = mask + ((long)(win & 255) * NTOK + lane) * NTOK;
    const int* rrow = rel_index + lane * NTOK;
    float s[NTOK];
    float mx = -1e30f;
#pragma unroll
    for (int m = 0; m < NTOK; ++m) {
      const short* kp = qk + m * 288 + CC + head * HDIM;
      float acc = 0.f;
#pragma unroll
      for (int jj = 0; jj < 4; ++jj) {
        short8 v8 = *(const short8*)(kp + jj * 8);
#pragma unroll
        for (int j = 0; j < 8; ++j) acc += q[jj * 8 + j] * bits2f(v8[j]);
      }
      acc += IO<T>::ld(bias_table, (long)rrow[m] * NHH + head);
      acc += IO<T>::ld(mrow, m);
      s[m] = acc;
      mx = fmaxf(mx, acc);
    }
    float sum = 0.f;
#pragma unroll
    for (int m = 0; m < NTOK; ++m) {
      float e = __expf(s[m] - mx);
      s[m] = e;
      sum += e;
    }
    float inv = 1.f / sum;
    float o[HDIM];
#pragma unroll
    for (int d = 0; d < HDIM; ++d) o[d] = 0.f;
#pragma unroll
    for (int m = 0; m < NTOK; ++m) {
      const short* vp = qk + m * 288 + 2 * CC + head * HDIM;
      float p = s[m];
#pragma unroll
      for (int jj = 0; jj < 4; ++jj) {
        short8 v8 = *(const short8*)(vp + jj * 8);
#pragma unroll
        for (int j = 0; j < 8; ++j) o[jj * 8 + j] += p * bits2f(v8[j]);
      }
    }
    bf16* op = attn_out + ((long)win * NTOK + lane) * CC + head * HDIM;
#pragma unroll
    for (int d = 0; d < HDIM; ++d) op[d] = f2bf(o[d] * inv);
  }
}

// ---------------------------------------------------------------------------
// window reverse + reverse shift index for token m (window order) -> image
// ---------------------------------------------------------------------------
static __device__ __forceinline__ long scatter_index(long m) {
  int win = (int)(m / NTOK);
  int n = (int)(m - (long)win * NTOK);
  int bq = win >> 8, wi = win & 255;
  int wh = wi >> 4, ww = wi & 15;
  int i = n / WSZ, j = n - (n / WSZ) * WSZ;
  int hf = wh * WSZ + i + SHIFT_; if (hf >= HH) hf -= HH;
  int wf = ww * WSZ + j + SHIFT_; if (wf >= WW_) wf -= WW_;
  return ((long)bq * (HH * WW_) + (long)hf * WW_ + wf) * CC;
}

// ---------------------------------------------------------------------------
// Proj GEMM (96x96) + window-reverse scatter + shortcut add; x1 -> out (d_out,
// type T). W staged in LDS as bf16.
// ---------------------------------------------------------------------------
template <typename T>
__global__ __launch_bounds__(256) void proj_kernel(
    const int* __restrict__ flag, const bf16* __restrict__ A,
    const T* __restrict__ W, const T* __restrict__ bias, T* __restrict__ out,
    const T* __restrict__ res) {
  if (*flag != IO<T>::kind) return;
  __shared__ short wl[CC * CC];
  __shared__ float bl[CC];
  for (int i = threadIdx.x; i < CC * CC; i += 256) wl[i] = f2bits(IO<T>::ld(W, i));
  for (int i = threadIdx.x; i < CC; i += 256) bl[i] = IO<T>::ld(bias, i);
  __syncthreads();
  int wave = threadIdx.x >> 6;
  int lane = threadIdx.x & 63;
  int col = lane & 15;
  int kg = lane >> 4;
  long mbase = (long)blockIdx.x * 128 + wave * 32;
  short8 a0[3], a1[3];
#pragma unroll
  for (int kc = 0; kc < 3; ++kc) {
    a0[kc] = *(const short8*)(A + (mbase + col) * CC + kc * 32 + kg * 8);
    a1[kc] = *(const short8*)(A + (mbase + 16 + col) * CC + kc * 32 + kg * 8);
  }
  long dst0[4], dst1[4];
#pragma unroll
  for (int r = 0; r < 4; ++r) {
    dst0[r] = scatter_index(mbase + kg * 4 + r);
    dst1[r] = scatter_index(mbase + 16 + kg * 4 + r);
  }
  for (int nc = 0; nc < 6; ++nc) {
    floatx4 acc0 = {0.f, 0.f, 0.f, 0.f};
    floatx4 acc1 = {0.f, 0.f, 0.f, 0.f};
#pragma unroll
    for (int kc = 0; kc < 3; ++kc) {
      short8 bfr = *(const short8*)(wl + (nc * 16 + col) * CC + kc * 32 + kg * 8);
      acc0 = __builtin_amdgcn_mfma_f32_16x16x32_bf16(a0[kc], bfr, acc0, 0, 0, 0);
      acc1 = __builtin_amdgcn_mfma_f32_16x16x32_bf16(a1[kc], bfr, acc1, 0, 0, 0);
    }
    int cc = nc * 16 + col;
    float bb = bl[cc];
#pragma unroll
    for (int r = 0; r < 4; ++r) {
      long p0 = dst0[r] + cc;
      long p1 = dst1[r] + cc;
      IO<T>::st(out, p0, acc0[r] + bb + IO<T>::ld(res, p0));
      IO<T>::st(out, p1, acc1[r] + bb + IO<T>::ld(res, p1));
    }
  }
}

// ---------------------------------------------------------------------------
// Fused MLP: h1 = gelu(y @ fc1_w.T + b1) per-wave in LDS (bf16), then
// out = h1 @ fc2_w.T + b2 + x1 (x1 read from d_out, result written back).
// One wave per 16 rows; block = 64 rows.
// ---------------------------------------------------------------------------
template <typename T>
__global__ __launch_bounds__(256) void mlp_kernel(
    const int* __restrict__ flag, const bf16* __restrict__ y,
    const T* __restrict__ fc1_w, const T* __restrict__ fc1_b,
    const T* __restrict__ fc2_w, const T* __restrict__ fc2_b,
    T* __restrict__ xo) {
  if (*flag != IO<T>::kind) return;
  __shared__ short h1[4 * 16 * 384];  // 49152 B, per-wave 16x384 tile
  int wave = threadIdx.x >> 6;
  int lane = threadIdx.x & 63;
  int col = lane & 15;
  int kg = lane >> 4;
  long mbase = (long)blockIdx.x * 64 + wave * 16;
  short* hw = h1 + wave * 16 * 384;
  short8 af[3];
#pragma unroll
  for (int kc = 0; kc < 3; ++kc)
    af[kc] = *(const short8*)(y + (mbase + col) * CC + kc * 32 + kg * 8);
  for (int nc = 0; nc < 24; ++nc) {
    floatx4 acc = {0.f, 0.f, 0.f, 0.f};
#pragma unroll
    for (int kc = 0; kc < 3; ++kc) {
      short8 bfr = IO<T>::frag(fc1_w + (long)(nc * 16 + col) * CC + kc * 32 + kg * 8);
      acc = __builtin_amdgcn_mfma_f32_16x16x32_bf16(af[kc], bfr, acc, 0, 0, 0);
    }
    int cc = nc * 16 + col;
    float bb = IO<T>::ld(fc1_b, cc);
#pragma unroll
    for (int r = 0; r < 4; ++r) {
      float v = acc[r] + bb;
      float ge = 0.5f * v * (1.f + erff(v * 0.70710678118654752f));
      hw[(kg * 4 + r) * 384 + cc] = f2bits(ge);
    }
  }
  __syncthreads();
  for (int nc2 = 0; nc2 < 6; ++nc2) {
    floatx4 acc = {0.f, 0.f, 0.f, 0.f};
#pragma unroll
    for (int kc2 = 0; kc2 < 12; ++kc2) {
      short8 a2 = *(const short8*)(hw + col * 384 + kc2 * 32 + kg * 8);
      short8 b2 = IO<T>::frag(fc2_w + (long)(nc2 * 16 + col) * 384 + kc2 * 32 + kg * 8);
      acc = __builtin_amdgcn_mfma_f32_16x16x32_bf16(a2, b2, acc, 0, 0, 0);
    }
    int cc = nc2 * 16 + col;
    float bb = IO<T>::ld(fc2_b, cc);
#pragma unroll
    for (int r = 0; r < 4; ++r) {
      long p = (mbase + kg * 4 + r) * CC + cc;
      IO<T>::st(xo, p, acc[r] + bb + IO<T>::ld(xo, p));
    }
  }
}

// ---------------------------------------------------------------------------
template <typename T>
static void launch_all(void* const* d_in, void* d_out, bf16* bufA,
                       const int* flag, hipStream_t stream) {
  const T* x = (const T*)d_in[0];
  const T* attn_mask = (const T*)d_in[1];
  const int* rel_index = (const int*)d_in[2];
  const T* n1g = (const T*)d_in[3];
  const T* n1b = (const T*)d_in[4];
  const T* qkv_w = (const T*)d_in[5];
  const T* qkv_b = (const T*)d_in[6];
  const T* proj_w = (const T*)d_in[7];
  const T* proj_b = (const T*)d_in[8];
  const T* relt = (const T*)d_in[9];
  const T* n2g = (const T*)d_in[10];
  const T* n2b = (const T*)d_in[11];
  const T* fc1_w = (const T*)d_in[12];
  const T* fc1_b = (const T*)d_in[13];
  const T* fc2_w = (const T*)d_in[14];
  const T* fc2_b = (const T*)d_in[15];
  T* outp = (T*)d_out;

  // 1. LN1 + shift + window partition -> bufA (xw)
  ln_kernel<T, 1><<<MTOT / 4, 256, 0, stream>>>(flag, x, n1g, n1b, bufA);
  // 2. fused QKV + attention, in-place on bufA
  qkv_attn_kernel<T><<<WTOT, 256, 0, stream>>>(flag, bufA, qkv_w, qkv_b,
                                               attn_mask, rel_index, relt, bufA);
  // 3. proj + scatter + shortcut -> x1 parked in d_out
  proj_kernel<T><<<MTOT / 128, 256, 0, stream>>>(flag, bufA, proj_w, proj_b,
                                                 outp, x);
  // 4. LN2: d_out -> bufA (y)
  ln_kernel<T, 0><<<MTOT / 4, 256, 0, stream>>>(flag, outp, n2g, n2b, bufA);
  // 5. fused MLP: bufA + d_out(x1) -> d_out
  mlp_kernel<T><<<MTOT / 64, 256, 0, stream>>>(flag, bufA, fc1_w, fc1_b, fc2_w,
                                               fc2_b, outp);
}

extern "C" void kernel_launch(void* const* d_in, const int* in_sizes, int n_in,
                              void* d_out, int out_size, void* d_ws, size_t ws_size,
                              hipStream_t stream) {
  (void)in_sizes; (void)n_in; (void)out_size; (void)ws_size;
  char* ws = (char*)d_ws;
  bf16* bufA = (bf16*)ws;                           // MTOT*96 bf16 = 77 MB
  int* flag = (int*)(ws + (size_t)MTOT * CC * 2);   // 4 B after bufA

  detect_kernel<<<1, 256, 0, stream>>>((const unsigned short*)d_in[0], flag);
  launch_all<bf16>(d_in, d_out, bufA, flag, stream);
  launch_all<float>(d_in, d_out, bufA, flag, stream);
}

// Round 3
// 1822.793 us; speedup vs baseline: 1.3402x; 1.3402x over previous
//
#include <hip/hip_runtime.h>
#include <hip/hip_bf16.h>
#include <math.h>

#define HH 112
#define WW_ 112
#define CC 96
#define NHH 3
#define WSZ 7
#define SHIFT_ 3
#define NTOK 49
#define HDIM 32
#define WTOT 8192          // total windows = B * 16 * 16
#define MTOT 401408        // WTOT * NTOK

typedef __hip_bfloat16 bf16;
typedef __attribute__((ext_vector_type(8))) short short8;
typedef __attribute__((ext_vector_type(4))) float floatx4;

static __device__ __forceinline__ float bits2f(short s) {
  return __uint_as_float(((unsigned)(unsigned short)s) << 16);
}
static __device__ __forceinline__ short f2bits(float v) {
  bf16 h = __float2bfloat16(v);
  short s;
  __builtin_memcpy(&s, &h, 2);
  return s;
}
static __device__ __forceinline__ float bf2f(bf16 v) { return __bfloat162float(v); }
static __device__ __forceinline__ bf16 f2bf(float v) { return __float2bfloat16(v); }

template <typename T> struct IO;
template <> struct IO<float> {
  static __device__ __forceinline__ float ld(const float* p, long i) { return p[i]; }
  static __device__ __forceinline__ void st(float* p, long i, float v) { p[i] = v; }
  static __device__ __forceinline__ short8 frag(const float* p) {
    short8 r;
#pragma unroll
    for (int j = 0; j < 8; ++j) r[j] = f2bits(p[j]);
    return r;
  }
};
template <> struct IO<bf16> {
  static __device__ __forceinline__ float ld(const bf16* p, long i) { return bf2f(p[i]); }
  static __device__ __forceinline__ void st(bf16* p, long i, float v) { p[i] = f2bf(v); }
  static __device__ __forceinline__ short8 frag(const bf16* p) { return *(const short8*)p; }
};

// ---------------------------------------------------------------------------
// dtype detection: flag = 1 if input is f32, 0 if bf16.
// ---------------------------------------------------------------------------
__global__ void detect_kernel(const unsigned short* __restrict__ x, int* flag) {
  __shared__ int tot;
  if (threadIdx.x == 0) tot = 0;
  __syncthreads();
  int bad = 0;
  for (int i = threadIdx.x; i < 8192; i += 256) {
    int e = (x[i] >> 7) & 0xFF;
    if (e >= 0x86) bad++;  // |value| >= 128 (or inf/nan)
  }
  atomicAdd(&tot, bad);
  __syncthreads();
  if (threadIdx.x == 0) *flag = (tot > 64) ? 1 : 0;
}

// ---------------------------------------------------------------------------
// Combined bias+mask table: comb[wi][h][m][n] = bias_table[rel_index[m,n], h]
//                                              + attn_mask[wi, m, n]   (bf16)
// ---------------------------------------------------------------------------
template <typename T>
__device__ __forceinline__ void combine_body(const T* mask, const int* rel,
                                             const T* bt, bf16* comb) {
  long idx = (long)blockIdx.x * 256 + threadIdx.x;  // [wi][h][2401]
  long rem = idx % 7203;
  long wi = idx / 7203;
  int h = (int)(rem / 2401);
  int n2 = (int)(rem % 2401);
  float v = IO<T>::ld(bt, (long)rel[n2] * NHH + h) + IO<T>::ld(mask, wi * 2401 + n2);
  comb[idx] = f2bf(v);
}
__global__ __launch_bounds__(256) void combine_kernel(
    const int* __restrict__ flag, const void* mask, const int* __restrict__ rel,
    const void* bt, bf16* __restrict__ comb) {
  if (*flag)
    combine_body<float>((const float*)mask, rel, (const float*)bt, comb);
  else
    combine_body<bf16>((const bf16*)mask, rel, (const bf16*)bt, comb);
}

// ---------------------------------------------------------------------------
// LN: one wave per token. GATHER=1 fuses cyclic shift + window partition.
// ---------------------------------------------------------------------------
template <typename T, int GATHER>
__device__ __forceinline__ void ln_body(const T* x, const T* g, const T* b,
                                        bf16* out) {
  int wid = threadIdx.x >> 6;
  int lane = threadIdx.x & 63;
  long t = (long)blockIdx.x * 4 + wid;  // token index in OUTPUT order
  const T* src;
  if (GATHER) {
    int win = (int)(t / NTOK);
    int n = (int)(t - (long)win * NTOK);
    int bq = win >> 8, wi = win & 255;
    int wh = wi >> 4, ww = wi & 15;
    int i = n / WSZ, j = n - (n / WSZ) * WSZ;
    int hs = wh * WSZ + i + SHIFT_; if (hs >= HH) hs -= HH;
    int ws = ww * WSZ + j + SHIFT_; if (ws >= WW_) ws -= WW_;
    src = x + ((long)bq * (HH * WW_) + (long)hs * WW_ + ws) * CC;
  } else {
    src = x + t * CC;
  }
  float v0 = IO<T>::ld(src, lane);
  float v1 = (lane < 32) ? IO<T>::ld(src, 64 + lane) : 0.f;
  float s = v0 + v1;
#pragma unroll
  for (int m = 32; m; m >>= 1) s += __shfl_xor(s, m, 64);
  float mean = s * (1.f / CC);
  float d0 = v0 - mean;
  float d1 = v1 - mean;
  float sq = d0 * d0 + ((lane < 32) ? d1 * d1 : 0.f);
#pragma unroll
  for (int m = 32; m; m >>= 1) sq += __shfl_xor(sq, m, 64);
  float rstd = rsqrtf(sq * (1.f / CC) + 1e-5f);
  bf16* dst = out + t * CC;
  dst[lane] = f2bf(d0 * rstd * IO<T>::ld(g, lane) + IO<T>::ld(b, lane));
  if (lane < 32)
    dst[64 + lane] =
        f2bf(d1 * rstd * IO<T>::ld(g, 64 + lane) + IO<T>::ld(b, 64 + lane));
}
template <int GATHER>
__global__ __launch_bounds__(256) void ln_kernel(
    const int* __restrict__ flag, const void* x, const void* g, const void* b,
    bf16* __restrict__ out) {
  if (*flag)
    ln_body<float, GATHER>((const float*)x, (const float*)g, (const float*)b, out);
  else
    ln_body<bf16, GATHER>((const bf16*)x, (const bf16*)g, (const bf16*)b, out);
}

// ---------------------------------------------------------------------------
// Fused QKV GEMM + MFMA window attention. One block per window.
// Phase 1: 4 waves compute qkv (64x288, rows>=49 padded via row clamp) into
//          LDS via MFMA; Q is pre-scaled by 1/sqrt(HDIM).
// Phase 2: wave w = m-tile w; for each head: S stripe (16x64) = Q K^T via
//          4 MFMAs (HDIM=32 = one K-chunk), held in registers.
// Phase 3: softmax per row (cols >=49 masked to -inf), probabilities written
//          as bf16 into the now-dead Q|K LDS region (overlay, stride 288).
// Phase 4: O = P V via MFMA (K dim = 64, pad cols have P=0), store rows <49.
// ---------------------------------------------------------------------------
template <typename T>
__device__ __forceinline__ void qkv_attn_body(
    const bf16* xw, const T* qkv_w, const T* qkv_b, const bf16* comb,
    bf16* attn_out, short* qk, float* bq) {
  const float scale = 0.17677669529663687f;  // 1/sqrt(32)
  int win = blockIdx.x;
  int wave = threadIdx.x >> 6;
  int lane = threadIdx.x & 63;
  int col = lane & 15;
  int kg = lane >> 4;
  for (int i = threadIdx.x; i < 288; i += 256) bq[i] = IO<T>::ld(qkv_b, i);
  long row = (long)win * NTOK + wave * 16 + col;
  if (row >= MTOT) row = MTOT - 1;  // pad rows: finite garbage, discarded
  short8 af[3];
#pragma unroll
  for (int kc = 0; kc < 3; ++kc)
    af[kc] = *(const short8*)(xw + row * CC + kc * 32 + kg * 8);
  __syncthreads();
  // ---- Phase 1: QKV ----
  for (int nc = 0; nc < 18; ++nc) {
    floatx4 acc = {0.f, 0.f, 0.f, 0.f};
#pragma unroll
    for (int kc = 0; kc < 3; ++kc) {
      short8 bfr = IO<T>::frag(qkv_w + (long)(nc * 16 + col) * CC + kc * 32 + kg * 8);
      acc = __builtin_amdgcn_mfma_f32_16x16x32_bf16(af[kc], bfr, acc, 0, 0, 0);
    }
    int cc = nc * 16 + col;
    float bb = bq[cc];
    float sc = (cc < CC) ? scale : 1.f;  // fold softmax scale into Q
#pragma unroll
    for (int r = 0; r < 4; ++r)
      qk[(wave * 16 + kg * 4 + r) * 288 + cc] = f2bits((acc[r] + bb) * sc);
  }
  __syncthreads();
  // ---- Phase 2: S = Q K^T (registers) ----
  int mt = wave;
  floatx4 st[3][4];
#pragma unroll
  for (int h = 0; h < NHH; ++h) {
    short8 qa = *(const short8*)(qk + (mt * 16 + col) * 288 + h * HDIM + kg * 8);
#pragma unroll
    for (int nt = 0; nt < 4; ++nt) {
      short8 kb = *(const short8*)(qk + (nt * 16 + col) * 288 + CC + h * HDIM + kg * 8);
      floatx4 z = {0.f, 0.f, 0.f, 0.f};
      st[h][nt] = __builtin_amdgcn_mfma_f32_16x16x32_bf16(qa, kb, z, 0, 0, 0);
    }
  }
  __syncthreads();  // Q,K region dead from here
  // ---- Phase 3: softmax + write P into overlay (cols 0..191) ----
  const bf16* cb = comb + (long)(win & 255) * (NHH * 2401);
#pragma unroll
  for (int h = 0; h < NHH; ++h) {
#pragma unroll
    for (int r = 0; r < 4; ++r) {
      int m = mt * 16 + kg * 4 + r;
      int mc = (m < NTOK) ? m : (NTOK - 1);
      float sv[4];
      float mx = -1e30f;
#pragma unroll
      for (int nt = 0; nt < 4; ++nt) {
        int n = nt * 16 + col;
        float v = (n < NTOK)
                      ? (st[h][nt][r] + bf2f(cb[h * 2401 + mc * NTOK + n]))
                      : -1e30f;
        sv[nt] = v;
        mx = fmaxf(mx, v);
      }
#pragma unroll
      for (int msk = 1; msk < 16; msk <<= 1) mx = fmaxf(mx, __shfl_xor(mx, msk, 64));
      float sum = 0.f;
#pragma unroll
      for (int nt = 0; nt < 4; ++nt) {
        float e = __expf(sv[nt] - mx);
        sv[nt] = e;
        sum += e;
      }
#pragma unroll
      for (int msk = 1; msk < 16; msk <<= 1) sum += __shfl_xor(sum, msk, 64);
      float inv = 1.f / sum;
#pragma unroll
      for (int nt = 0; nt < 4; ++nt)
        qk[m * 288 + h * 64 + nt * 16 + col] = f2bits(sv[nt] * inv);
    }
  }
  __syncthreads();
  // ---- Phase 4: O = P V ----
#pragma unroll
  for (int h = 0; h < NHH; ++h) {
    floatx4 oa[2];
    oa[0] = (floatx4){0.f, 0.f, 0.f, 0.f};
    oa[1] = (floatx4){0.f, 0.f, 0.f, 0.f};
#pragma unroll
    for (int kc = 0; kc < 2; ++kc) {
      short8 pa = *(const short8*)(qk + (mt * 16 + col) * 288 + h * 64 + kc * 32 + kg * 8);
#pragma unroll
      for (int dt = 0; dt < 2; ++dt) {
        short8 vb;
#pragma unroll
        for (int j = 0; j < 8; ++j)
          vb[j] = qk[(kc * 32 + kg * 8 + j) * 288 + 2 * CC + h * HDIM + dt * 16 + col];
        oa[dt] = __builtin_amdgcn_mfma_f32_16x16x32_bf16(pa, vb, oa[dt], 0, 0, 0);
      }
    }
#pragma unroll
    for (int dt = 0; dt < 2; ++dt)
#pragma unroll
      for (int r = 0; r < 4; ++r) {
        int m = mt * 16 + kg * 4 + r;
        if (m < NTOK)
          attn_out[((long)win * NTOK + m) * CC + h * HDIM + dt * 16 + col] =
              f2bf(oa[dt][r]);
      }
  }
}
__global__ __launch_bounds__(256) void qkv_attn_kernel(
    const int* __restrict__ flag, const bf16* __restrict__ xw,
    const void* qkv_w, const void* qkv_b, const bf16* __restrict__ comb,
    bf16* __restrict__ attn_out) {
  __shared__ short qk[64 * 288];
  __shared__ float bq[288];
  if (*flag)
    qkv_attn_body<float>(xw, (const float*)qkv_w, (const float*)qkv_b, comb,
                         attn_out, qk, bq);
  else
    qkv_attn_body<bf16>(xw, (const bf16*)qkv_w, (const bf16*)qkv_b, comb,
                        attn_out, qk, bq);
}

// ---------------------------------------------------------------------------
// window reverse + reverse shift index for token m (window order) -> image
// ---------------------------------------------------------------------------
static __device__ __forceinline__ long scatter_index(long m) {
  int win = (int)(m / NTOK);
  int n = (int)(m - (long)win * NTOK);
  int bq = win >> 8, wi = win & 255;
  int wh = wi >> 4, ww = wi & 15;
  int i = n / WSZ, j = n - (n / WSZ) * WSZ;
  int hf = wh * WSZ + i + SHIFT_; if (hf >= HH) hf -= HH;
  int wf = ww * WSZ + j + SHIFT_; if (wf >= WW_) wf -= WW_;
  return ((long)bq * (HH * WW_) + (long)hf * WW_ + wf) * CC;
}

// ---------------------------------------------------------------------------
// Proj GEMM (96x96) + window-reverse scatter + shortcut add -> out (d_out).
// ---------------------------------------------------------------------------
template <typename T>
__device__ __forceinline__ void proj_body(const bf16* A, const T* W,
                                          const T* bias, T* out, const T* res,
                                          short* wl, float* bl) {
  for (int i = threadIdx.x; i < CC * CC; i += 256) wl[i] = f2bits(IO<T>::ld(W, i));
  for (int i = threadIdx.x; i < CC; i += 256) bl[i] = IO<T>::ld(bias, i);
  __syncthreads();
  int wave = threadIdx.x >> 6;
  int lane = threadIdx.x & 63;
  int col = lane & 15;
  int kg = lane >> 4;
  long mbase = (long)blockIdx.x * 128 + wave * 32;
  short8 a0[3], a1[3];
#pragma unroll
  for (int kc = 0; kc < 3; ++kc) {
    a0[kc] = *(const short8*)(A + (mbase + col) * CC + kc * 32 + kg * 8);
    a1[kc] = *(const short8*)(A + (mbase + 16 + col) * CC + kc * 32 + kg * 8);
  }
  long dst0[4], dst1[4];
#pragma unroll
  for (int r = 0; r < 4; ++r) {
    dst0[r] = scatter_index(mbase + kg * 4 + r);
    dst1[r] = scatter_index(mbase + 16 + kg * 4 + r);
  }
  for (int nc = 0; nc < 6; ++nc) {
    floatx4 acc0 = {0.f, 0.f, 0.f, 0.f};
    floatx4 acc1 = {0.f, 0.f, 0.f, 0.f};
#pragma unroll
    for (int kc = 0; kc < 3; ++kc) {
      short8 bfr = *(const short8*)(wl + (nc * 16 + col) * CC + kc * 32 + kg * 8);
      acc0 = __builtin_amdgcn_mfma_f32_16x16x32_bf16(a0[kc], bfr, acc0, 0, 0, 0);
      acc1 = __builtin_amdgcn_mfma_f32_16x16x32_bf16(a1[kc], bfr, acc1, 0, 0, 0);
    }
    int cc = nc * 16 + col;
    float bb = bl[cc];
#pragma unroll
    for (int r = 0; r < 4; ++r) {
      long p0 = dst0[r] + cc;
      long p1 = dst1[r] + cc;
      IO<T>::st(out, p0, acc0[r] + bb + IO<T>::ld(res, p0));
      IO<T>::st(out, p1, acc1[r] + bb + IO<T>::ld(res, p1));
    }
  }
}
__global__ __launch_bounds__(256) void proj_kernel(
    const int* __restrict__ flag, const bf16* __restrict__ A, const void* W,
    const void* bias, void* out, const void* res) {
  __shared__ short wl[CC * CC];
  __shared__ float bl[CC];
  if (*flag)
    proj_body<float>(A, (const float*)W, (const float*)bias, (float*)out,
                     (const float*)res, wl, bl);
  else
    proj_body<bf16>(A, (const bf16*)W, (const bf16*)bias, (bf16*)out,
                    (const bf16*)res, wl, bl);
}

// ---------------------------------------------------------------------------
// Fused MLP: h1 = gelu(y @ fc1_w.T + b1) per-wave in LDS, then
// out = h1 @ fc2_w.T + b2 + x1 (x1 read from d_out, written back).
// ---------------------------------------------------------------------------
template <typename T>
__device__ __forceinline__ void mlp_body(const bf16* y, const T* fc1_w,
                                         const T* fc1_b, const T* fc2_w,
                                         const T* fc2_b, T* xo, short* h1) {
  int wave = threadIdx.x >> 6;
  int lane = threadIdx.x & 63;
  int col = lane & 15;
  int kg = lane >> 4;
  long mbase = (long)blockIdx.x * 64 + wave * 16;
  short* hw = h1 + wave * 16 * 384;
  short8 af[3];
#pragma unroll
  for (int kc = 0; kc < 3; ++kc)
    af[kc] = *(const short8*)(y + (mbase + col) * CC + kc * 32 + kg * 8);
  for (int nc = 0; nc < 24; ++nc) {
    floatx4 acc = {0.f, 0.f, 0.f, 0.f};
#pragma unroll
    for (int kc = 0; kc < 3; ++kc) {
      short8 bfr = IO<T>::frag(fc1_w + (long)(nc * 16 + col) * CC + kc * 32 + kg * 8);
      acc = __builtin_amdgcn_mfma_f32_16x16x32_bf16(af[kc], bfr, acc, 0, 0, 0);
    }
    int cc = nc * 16 + col;
    float bb = IO<T>::ld(fc1_b, cc);
#pragma unroll
    for (int r = 0; r < 4; ++r) {
      float v = acc[r] + bb;
      float ge = 0.5f * v * (1.f + erff(v * 0.70710678118654752f));
      hw[(kg * 4 + r) * 384 + cc] = f2bits(ge);
    }
  }
  __syncthreads();
  for (int nc2 = 0; nc2 < 6; ++nc2) {
    floatx4 acc = {0.f, 0.f, 0.f, 0.f};
#pragma unroll
    for (int kc2 = 0; kc2 < 12; ++kc2) {
      short8 a2 = *(const short8*)(hw + col * 384 + kc2 * 32 + kg * 8);
      short8 b2 = IO<T>::frag(fc2_w + (long)(nc2 * 16 + col) * 384 + kc2 * 32 + kg * 8);
      acc = __builtin_amdgcn_mfma_f32_16x16x32_bf16(a2, b2, acc, 0, 0, 0);
    }
    int cc = nc2 * 16 + col;
    float bb = IO<T>::ld(fc2_b, cc);
#pragma unroll
    for (int r = 0; r < 4; ++r) {
      long p = (mbase + kg * 4 + r) * CC + cc;
      IO<T>::st(xo, p, acc[r] + bb + IO<T>::ld(xo, p));
    }
  }
}
__global__ __launch_bounds__(256) void mlp_kernel(
    const int* __restrict__ flag, const bf16* __restrict__ y, const void* fc1_w,
    const void* fc1_b, const void* fc2_w, const void* fc2_b, void* xo) {
  __shared__ short h1[4 * 16 * 384];
  if (*flag)
    mlp_body<float>(y, (const float*)fc1_w, (const float*)fc1_b,
                    (const float*)fc2_w, (const float*)fc2_b, (float*)xo, h1);
  else
    mlp_body<bf16>(y, (const bf16*)fc1_w, (const bf16*)fc1_b,
                   (const bf16*)fc2_w, (const bf16*)fc2_b, (bf16*)xo, h1);
}

// ---------------------------------------------------------------------------
extern "C" void kernel_launch(void* const* d_in, const int* in_sizes, int n_in,
                              void* d_out, int out_size, void* d_ws, size_t ws_size,
                              hipStream_t stream) {
  (void)in_sizes; (void)n_in; (void)out_size; (void)ws_size;
  char* ws = (char*)d_ws;
  bf16* bufA = (bf16*)ws;                                   // MTOT*96 bf16 = 77 MB
  size_t offA = (size_t)MTOT * CC * 2;
  bf16* comb = (bf16*)(ws + offA);                          // 256*3*2401 bf16 = 3.7 MB
  size_t offC = offA + (size_t)256 * NHH * 2401 * 2;
  int* flag = (int*)(ws + offC);

  const int* rel_index = (const int*)d_in[2];

  detect_kernel<<<1, 256, 0, stream>>>((const unsigned short*)d_in[0], flag);
  // combined bias+mask table (dtype-aware)
  combine_kernel<<<7203, 256, 0, stream>>>(flag, d_in[1], rel_index, d_in[9], comb);
  // 1. LN1 + shift + window partition -> bufA (xw)
  ln_kernel<1><<<MTOT / 4, 256, 0, stream>>>(flag, d_in[0], d_in[3], d_in[4], bufA);
  // 2. fused QKV + MFMA attention, in-place on bufA
  qkv_attn_kernel<<<WTOT, 256, 0, stream>>>(flag, bufA, d_in[5], d_in[6], comb, bufA);
  // 3. proj + scatter + shortcut -> x1 parked in d_out
  proj_kernel<<<MTOT / 128, 256, 0, stream>>>(flag, bufA, d_in[7], d_in[8], d_out, d_in[0]);
  // 4. LN2: d_out -> bufA (y)
  ln_kernel<0><<<MTOT / 4, 256, 0, stream>>>(flag, d_out, d_in[10], d_in[11], bufA);
  // 5. fused MLP: bufA + d_out(x1) -> d_out
  mlp_kernel<<<MTOT / 64, 256, 0, stream>>>(flag, bufA, d_in[12], d_in[13],
                                            d_in[14], d_in[15], d_out);
}

// Round 4
// 815.608 us; speedup vs baseline: 2.9951x; 2.2349x over previous
//
#include <hip/hip_runtime.h>
#include <hip/hip_bf16.h>
#include <math.h>

#define HH 112
#define WW_ 112
#define CC 96
#define NHH 3
#define WSZ 7
#define SHIFT_ 3
#define NTOK 49
#define HDIM 32
#define WTOT 8192          // total windows = B * 16 * 16
#define MTOT 401408        // WTOT * NTOK

typedef __hip_bfloat16 bf16;
typedef __attribute__((ext_vector_type(8))) short short8;
typedef __attribute__((ext_vector_type(4))) float floatx4;

static __device__ __forceinline__ float bits2f(short s) {
  return __uint_as_float(((unsigned)(unsigned short)s) << 16);
}
static __device__ __forceinline__ short f2bits(float v) {
  bf16 h = __float2bfloat16(v);
  short s;
  __builtin_memcpy(&s, &h, 2);
  return s;
}
static __device__ __forceinline__ float bf2f(bf16 v) { return __bfloat162float(v); }
static __device__ __forceinline__ bf16 f2bf(float v) { return __float2bfloat16(v); }

template <typename T> struct IO;
template <> struct IO<float> {
  static __device__ __forceinline__ float ld(const float* p, long i) { return p[i]; }
  static __device__ __forceinline__ void st(float* p, long i, float v) { p[i] = v; }
  static __device__ __forceinline__ short8 frag(const float* p) {
    short8 r;
#pragma unroll
    for (int j = 0; j < 8; ++j) r[j] = f2bits(p[j]);
    return r;
  }
};
template <> struct IO<bf16> {
  static __device__ __forceinline__ float ld(const bf16* p, long i) { return bf2f(p[i]); }
  static __device__ __forceinline__ void st(bf16* p, long i, float v) { p[i] = f2bf(v); }
  static __device__ __forceinline__ short8 frag(const bf16* p) { return *(const short8*)p; }
};

// ---------------------------------------------------------------------------
// dtype detection: flag = 1 if input is f32, 0 if bf16.
// ---------------------------------------------------------------------------
__global__ void detect_kernel(const unsigned short* __restrict__ x, int* flag) {
  __shared__ int tot;
  if (threadIdx.x == 0) tot = 0;
  __syncthreads();
  int bad = 0;
  for (int i = threadIdx.x; i < 8192; i += 256) {
    int e = (x[i] >> 7) & 0xFF;
    if (e >= 0x86) bad++;  // |value| >= 128 (or inf/nan)
  }
  atomicAdd(&tot, bad);
  __syncthreads();
  if (threadIdx.x == 0) *flag = (tot > 64) ? 1 : 0;
}

// ---------------------------------------------------------------------------
// Combined bias+mask table: comb[wi][h][m][n] (bf16)
// ---------------------------------------------------------------------------
template <typename T>
__device__ __forceinline__ void combine_body(const T* mask, const int* rel,
                                             const T* bt, bf16* comb) {
  long idx = (long)blockIdx.x * 256 + threadIdx.x;  // [wi][h][2401]
  long rem = idx % 7203;
  long wi = idx / 7203;
  int h = (int)(rem / 2401);
  int n2 = (int)(rem % 2401);
  float v = IO<T>::ld(bt, (long)rel[n2] * NHH + h) + IO<T>::ld(mask, wi * 2401 + n2);
  comb[idx] = f2bf(v);
}
__global__ __launch_bounds__(256) void combine_kernel(
    const int* __restrict__ flag, const void* mask, const int* __restrict__ rel,
    const void* bt, bf16* __restrict__ comb) {
  if (*flag)
    combine_body<float>((const float*)mask, rel, (const float*)bt, comb);
  else
    combine_body<bf16>((const bf16*)mask, rel, (const bf16*)bt, comb);
}

// ---------------------------------------------------------------------------
// Fused LN1 + QKV GEMM + MFMA window attention. One block per window.
// LDS: qk[64][200]   Q cols 0..95 (prescaled), K cols 96..191; P overlay later
//      R[6656]       xln (64x104) first, then vT (96 x 68: V transposed)
//      wc[48*104]    weight chunk (gamma/beta overlay during LN)
//      bq[288]       qkv bias
// ---------------------------------------------------------------------------
template <typename T>
__device__ __forceinline__ void qkv_attn_body(
    const T* x, const T* g1, const T* b1, const T* qkv_w, const T* qkv_b,
    const bf16* comb, bf16* attn_out, short* qk, short* R, short* wc,
    float* bq) {
  int win = blockIdx.x;
  int wave = threadIdx.x >> 6;
  int lane = threadIdx.x & 63;
  int col = lane & 15, kg = lane >> 4;
  float* gb = (float*)wc;  // LN params overlay (dead before chunk staging)
  for (int i = threadIdx.x; i < 288; i += 256) bq[i] = IO<T>::ld(qkv_b, i);
  for (int i = threadIdx.x; i < CC; i += 256) {
    gb[i] = IO<T>::ld(g1, i);
    gb[CC + i] = IO<T>::ld(b1, i);
  }
  __syncthreads();
  // ---- LN1 + cyclic-shift gather -> xln (R region) ----
  {
    int r = lane >> 2;
    int seg = lane & 3;
    int n = wave * 16 + r;  // token in window (0..63)
    short* dst = R + n * 104 + seg * 24;
    if (n < NTOK) {
      int bq_ = win >> 8, wi = win & 255;
      int wh = wi >> 4, ww = wi & 15;
      int i = n / WSZ, j = n - (n / WSZ) * WSZ;
      int hs = wh * WSZ + i + SHIFT_; if (hs >= HH) hs -= HH;
      int ws = ww * WSZ + j + SHIFT_; if (ws >= WW_) ws -= WW_;
      const T* src = x + ((long)bq_ * (HH * WW_) + (long)hs * WW_ + ws) * CC + seg * 24;
      float a[24];
#pragma unroll
      for (int t = 0; t < 24; ++t) a[t] = IO<T>::ld(src, t);
      float s = 0.f;
#pragma unroll
      for (int t = 0; t < 24; ++t) s += a[t];
      s += __shfl_xor(s, 1, 64);
      s += __shfl_xor(s, 2, 64);
      float mean = s * (1.f / CC);
      float var = 0.f;
#pragma unroll
      for (int t = 0; t < 24; ++t) { float d = a[t] - mean; var += d * d; }
      var += __shfl_xor(var, 1, 64);
      var += __shfl_xor(var, 2, 64);
      float rstd = rsqrtf(var * (1.f / CC) + 1e-5f);
#pragma unroll
      for (int t = 0; t < 24; ++t)
        dst[t] = f2bits((a[t] - mean) * rstd * gb[seg * 24 + t] + gb[CC + seg * 24 + t]);
    } else {
#pragma unroll
      for (int t = 0; t < 24; ++t) dst[t] = 0;
    }
  }
  __syncthreads();
  short8 af[3];
#pragma unroll
  for (int kc = 0; kc < 3; ++kc)
    af[kc] = *(const short8*)(R + (wave * 16 + col) * 104 + kc * 32 + kg * 8);
  const float scale = 0.17677669529663687f;  // 1/sqrt(32)
  // ---- Phase 1: QKV, 6 weight chunks of 48 out-cols ----
  for (int c = 0; c < 6; ++c) {
    __syncthreads();
    for (int idx = threadIdx.x; idx < 576; idx += 256) {
      int r = idx / 12, c8 = idx % 12;
      *(short8*)(wc + r * 104 + c8 * 8) =
          IO<T>::frag(qkv_w + (long)(c * 48 + r) * CC + c8 * 8);
    }
    __syncthreads();
#pragma unroll
    for (int t = 0; t < 3; ++t) {
      floatx4 acc = {0.f, 0.f, 0.f, 0.f};
#pragma unroll
      for (int kc = 0; kc < 3; ++kc) {
        short8 bfr = *(const short8*)(wc + (t * 16 + col) * 104 + kc * 32 + kg * 8);
        acc = __builtin_amdgcn_mfma_f32_16x16x32_bf16(af[kc], bfr, acc, 0, 0, 0);
      }
      int nc = c * 3 + t;
      int cc = nc * 16 + col;
      float bb = bq[cc];
      if (nc < 6) {  // Q (prescale)
#pragma unroll
        for (int r = 0; r < 4; ++r)
          qk[(wave * 16 + kg * 4 + r) * 200 + cc] = f2bits((acc[r] + bb) * scale);
      } else if (nc < 12) {  // K
#pragma unroll
        for (int r = 0; r < 4; ++r)
          qk[(wave * 16 + kg * 4 + r) * 200 + cc] = f2bits(acc[r] + bb);
      } else {  // V -> transposed vT[d][token]
        int d = cc - 2 * CC;
#pragma unroll
        for (int r = 0; r < 4; ++r)
          R[d * 68 + wave * 16 + kg * 4 + r] = f2bits(acc[r] + bb);
      }
    }
  }
  __syncthreads();
  // ---- Phase 2: S = Q K^T (registers) ----
  floatx4 st[3][4];
#pragma unroll
  for (int h = 0; h < NHH; ++h) {
    short8 qa = *(const short8*)(qk + (wave * 16 + col) * 200 + h * HDIM + kg * 8);
#pragma unroll
    for (int nt = 0; nt < 4; ++nt) {
      short8 kb = *(const short8*)(qk + (nt * 16 + col) * 200 + CC + h * HDIM + kg * 8);
      floatx4 z = {0.f, 0.f, 0.f, 0.f};
      st[h][nt] = __builtin_amdgcn_mfma_f32_16x16x32_bf16(qa, kb, z, 0, 0, 0);
    }
  }
  __syncthreads();  // Q,K region dead
  // ---- Phase 3: softmax, P overlay into qk cols 0..191 ----
  const bf16* cb = comb + (long)(win & 255) * (NHH * 2401);
#pragma unroll
  for (int h = 0; h < NHH; ++h) {
#pragma unroll
    for (int r = 0; r < 4; ++r) {
      int m = wave * 16 + kg * 4 + r;
      int mc = (m < NTOK) ? m : (NTOK - 1);
      float sv[4];
      float mx = -1e30f;
#pragma unroll
      for (int nt = 0; nt < 4; ++nt) {
        int n = nt * 16 + col;
        float v = (n < NTOK)
                      ? (st[h][nt][r] + bf2f(cb[h * 2401 + mc * NTOK + n]))
                      : -1e30f;
        sv[nt] = v;
        mx = fmaxf(mx, v);
      }
#pragma unroll
      for (int msk = 1; msk < 16; msk <<= 1) mx = fmaxf(mx, __shfl_xor(mx, msk, 64));
      float sum = 0.f;
#pragma unroll
      for (int nt = 0; nt < 4; ++nt) {
        float e = __expf(sv[nt] - mx);
        sv[nt] = e;
        sum += e;
      }
#pragma unroll
      for (int msk = 1; msk < 16; msk <<= 1) sum += __shfl_xor(sum, msk, 64);
      float inv = 1.f / sum;
#pragma unroll
      for (int nt = 0; nt < 4; ++nt)
        qk[m * 200 + h * 64 + nt * 16 + col] = f2bits(sv[nt] * inv);
    }
  }
  __syncthreads();
  // ---- Phase 4: O = P V (vT gives contiguous B-frags) ----
#pragma unroll
  for (int h = 0; h < NHH; ++h) {
    floatx4 oa[2];
    oa[0] = (floatx4){0.f, 0.f, 0.f, 0.f};
    oa[1] = (floatx4){0.f, 0.f, 0.f, 0.f};
#pragma unroll
    for (int kc = 0; kc < 2; ++kc) {
      short8 pa = *(const short8*)(qk + (wave * 16 + col) * 200 + h * 64 + kc * 32 + kg * 8);
#pragma unroll
      for (int dt = 0; dt < 2; ++dt) {
        short8 vb = *(const short8*)(R + (h * HDIM + dt * 16 + col) * 68 + kc * 32 + kg * 8);
        oa[dt] = __builtin_amdgcn_mfma_f32_16x16x32_bf16(pa, vb, oa[dt], 0, 0, 0);
      }
    }
#pragma unroll
    for (int dt = 0; dt < 2; ++dt)
#pragma unroll
      for (int r = 0; r < 4; ++r) {
        int m = wave * 16 + kg * 4 + r;
        if (m < NTOK)
          attn_out[((long)win * NTOK + m) * CC + h * HDIM + dt * 16 + col] =
              f2bf(oa[dt][r]);
      }
  }
}
__global__ __launch_bounds__(256) void qkv_attn_kernel(
    const int* __restrict__ flag, const void* x, const void* g1, const void* b1,
    const void* qkv_w, const void* qkv_b, const bf16* __restrict__ comb,
    bf16* __restrict__ attn_out) {
  __shared__ short qk[64 * 200];
  __shared__ short R[6656];
  __shared__ short wc[48 * 104];
  __shared__ float bq[288];
  if (*flag)
    qkv_attn_body<float>((const float*)x, (const float*)g1, (const float*)b1,
                         (const float*)qkv_w, (const float*)qkv_b, comb,
                         attn_out, qk, R, wc, bq);
  else
    qkv_attn_body<bf16>((const bf16*)x, (const bf16*)g1, (const bf16*)b1,
                        (const bf16*)qkv_w, (const bf16*)qkv_b, comb, attn_out,
                        qk, R, wc, bq);
}

// ---------------------------------------------------------------------------
// window reverse + reverse shift index for token m (window order) -> image
// ---------------------------------------------------------------------------
static __device__ __forceinline__ long scatter_index(long m) {
  int win = (int)(m / NTOK);
  int n = (int)(m - (long)win * NTOK);
  int bq = win >> 8, wi = win & 255;
  int wh = wi >> 4, ww = wi & 15;
  int i = n / WSZ, j = n - (n / WSZ) * WSZ;
  int hf = wh * WSZ + i + SHIFT_; if (hf >= HH) hf -= HH;
  int wf = ww * WSZ + j + SHIFT_; if (wf >= WW_) wf -= WW_;
  return ((long)bq * (HH * WW_) + (long)hf * WW_ + wf) * CC;
}

// ---------------------------------------------------------------------------
// Proj GEMM (96x96, W staged padded in LDS) + scatter + shortcut add -> d_out
// ---------------------------------------------------------------------------
template <typename T>
__device__ __forceinline__ void proj_body(const bf16* A, const T* W,
                                          const T* bias, T* out, const T* res,
                                          short* wl, float* bl) {
  for (int idx = threadIdx.x; idx < 1152; idx += 256) {
    int r = idx / 12, c8 = idx % 12;
    *(short8*)(wl + r * 104 + c8 * 8) = IO<T>::frag(W + (long)r * CC + c8 * 8);
  }
  for (int i = threadIdx.x; i < CC; i += 256) bl[i] = IO<T>::ld(bias, i);
  __syncthreads();
  int wave = threadIdx.x >> 6;
  int lane = threadIdx.x & 63;
  int col = lane & 15;
  int kg = lane >> 4;
  long mbase = (long)blockIdx.x * 128 + wave * 32;
  short8 a0[3], a1[3];
#pragma unroll
  for (int kc = 0; kc < 3; ++kc) {
    a0[kc] = *(const short8*)(A + (mbase + col) * CC + kc * 32 + kg * 8);
    a1[kc] = *(const short8*)(A + (mbase + 16 + col) * CC + kc * 32 + kg * 8);
  }
  long dst0[4], dst1[4];
#pragma unroll
  for (int r = 0; r < 4; ++r) {
    dst0[r] = scatter_index(mbase + kg * 4 + r);
    dst1[r] = scatter_index(mbase + 16 + kg * 4 + r);
  }
#pragma unroll
  for (int nc = 0; nc < 6; ++nc) {
    floatx4 acc0 = {0.f, 0.f, 0.f, 0.f};
    floatx4 acc1 = {0.f, 0.f, 0.f, 0.f};
#pragma unroll
    for (int kc = 0; kc < 3; ++kc) {
      short8 bfr = *(const short8*)(wl + (nc * 16 + col) * 104 + kc * 32 + kg * 8);
      acc0 = __builtin_amdgcn_mfma_f32_16x16x32_bf16(a0[kc], bfr, acc0, 0, 0, 0);
      acc1 = __builtin_amdgcn_mfma_f32_16x16x32_bf16(a1[kc], bfr, acc1, 0, 0, 0);
    }
    int cc = nc * 16 + col;
    float bb = bl[cc];
#pragma unroll
    for (int r = 0; r < 4; ++r) {
      long p0 = dst0[r] + cc;
      long p1 = dst1[r] + cc;
      IO<T>::st(out, p0, acc0[r] + bb + IO<T>::ld(res, p0));
      IO<T>::st(out, p1, acc1[r] + bb + IO<T>::ld(res, p1));
    }
  }
}
__global__ __launch_bounds__(256) void proj_kernel(
    const int* __restrict__ flag, const bf16* __restrict__ A, const void* W,
    const void* bias, void* out, const void* res) {
  __shared__ short wl[96 * 104];
  __shared__ float bl[CC];
  if (*flag)
    proj_body<float>(A, (const float*)W, (const float*)bias, (float*)out,
                     (const float*)res, wl, bl);
  else
    proj_body<bf16>(A, (const bf16*)W, (const bf16*)bias, (bf16*)out,
                    (const bf16*)res, wl, bl);
}

// ---------------------------------------------------------------------------
// Fused LN2 + MLP. One block = 64 rows. FC1/FC2 processed in 6 chunks of 64
// hidden cols; weights staged cooperatively in LDS; h1 chunk round-trips
// through a small padded LDS tile; FC2 accumulates across chunks in regs.
// ---------------------------------------------------------------------------
template <typename T>
__device__ __forceinline__ void mlp_body(const T* n2g, const T* n2b,
                                         const T* fc1_w, const T* fc1_b,
                                         const T* fc2_w, const T* fc2_b, T* xo,
                                         short* xln, short* w1c, short* w2c) {
  int wave = threadIdx.x >> 6;
  int lane = threadIdx.x & 63;
  int col = lane & 15;
  int kg = lane >> 4;
  long mbase = (long)blockIdx.x * 64;
  float* gb = (float*)w2c;  // LN params overlay (dead before chunk staging)
  for (int i = threadIdx.x; i < CC; i += 256) {
    gb[i] = IO<T>::ld(n2g, i);
    gb[CC + i] = IO<T>::ld(n2b, i);
  }
  __syncthreads();
  // ---- LN2 on x1 (= xo) -> xln ----
  {
    int r = lane >> 2;
    int seg = lane & 3;
    const T* src = xo + (mbase + wave * 16 + r) * CC + seg * 24;
    float a[24];
#pragma unroll
    for (int t = 0; t < 24; ++t) a[t] = IO<T>::ld(src, t);
    float s = 0.f;
#pragma unroll
    for (int t = 0; t < 24; ++t) s += a[t];
    s += __shfl_xor(s, 1, 64);
    s += __shfl_xor(s, 2, 64);
    float mean = s * (1.f / CC);
    float var = 0.f;
#pragma unroll
    for (int t = 0; t < 24; ++t) { float d = a[t] - mean; var += d * d; }
    var += __shfl_xor(var, 1, 64);
    var += __shfl_xor(var, 2, 64);
    float rstd = rsqrtf(var * (1.f / CC) + 1e-5f);
    short* dst = xln + (wave * 16 + r) * 104 + seg * 24;
#pragma unroll
    for (int t = 0; t < 24; ++t)
      dst[t] = f2bits((a[t] - mean) * rstd * gb[seg * 24 + t] + gb[CC + seg * 24 + t]);
  }
  __syncthreads();
  short8 af[3];
#pragma unroll
  for (int kc = 0; kc < 3; ++kc)
    af[kc] = *(const short8*)(xln + (wave * 16 + col) * 104 + kc * 32 + kg * 8);
  short* h1c = xln;  // xln dead after af; reuse as h1 chunk (64 x 72)
  floatx4 acc2[6];
#pragma unroll
  for (int i = 0; i < 6; ++i) acc2[i] = (floatx4){0.f, 0.f, 0.f, 0.f};
  for (int c = 0; c < 6; ++c) {
    __syncthreads();  // prev chunk fully consumed (and af loaded, c=0)
    for (int idx = threadIdx.x; idx < 768; idx += 256) {
      int r = idx / 12, c8 = idx % 12;
      *(short8*)(w1c + r * 104 + c8 * 8) =
          IO<T>::frag(fc1_w + (long)(c * 64 + r) * CC + c8 * 8);
    }
    for (int idx = threadIdx.x; idx < 768; idx += 256) {
      int r = idx / 8, c8 = idx % 8;
      *(short8*)(w2c + r * 72 + c8 * 8) =
          IO<T>::frag(fc2_w + (long)r * 384 + c * 64 + c8 * 8);
    }
    __syncthreads();
    // FC1 chunk: 4 n-tiles -> gelu -> h1c
#pragma unroll
    for (int t = 0; t < 4; ++t) {
      floatx4 acc = {0.f, 0.f, 0.f, 0.f};
#pragma unroll
      for (int kc = 0; kc < 3; ++kc) {
        short8 bfr = *(const short8*)(w1c + (t * 16 + col) * 104 + kc * 32 + kg * 8);
        acc = __builtin_amdgcn_mfma_f32_16x16x32_bf16(af[kc], bfr, acc, 0, 0, 0);
      }
      float bb = IO<T>::ld(fc1_b, c * 64 + t * 16 + col);
#pragma unroll
      for (int r = 0; r < 4; ++r) {
        float v = acc[r] + bb;
        float ge = 0.5f * v * (1.f + erff(v * 0.70710678118654752f));
        h1c[(wave * 16 + kg * 4 + r) * 72 + t * 16 + col] = f2bits(ge);
      }
    }
    __syncthreads();
    // FC2 partial: this 64-wide K-chunk
    short8 a2[2];
#pragma unroll
    for (int kk = 0; kk < 2; ++kk)
      a2[kk] = *(const short8*)(h1c + (wave * 16 + col) * 72 + kk * 32 + kg * 8);
#pragma unroll
    for (int nc2 = 0; nc2 < 6; ++nc2) {
#pragma unroll
      for (int kk = 0; kk < 2; ++kk) {
        short8 b2f = *(const short8*)(w2c + (nc2 * 16 + col) * 72 + kk * 32 + kg * 8);
        acc2[nc2] = __builtin_amdgcn_mfma_f32_16x16x32_bf16(a2[kk], b2f, acc2[nc2], 0, 0, 0);
      }
    }
  }
  // ---- epilogue: + fc2_b + residual(x1), write back ----
#pragma unroll
  for (int nc2 = 0; nc2 < 6; ++nc2) {
    int cc = nc2 * 16 + col;
    float bb = IO<T>::ld(fc2_b, cc);
#pragma unroll
    for (int r = 0; r < 4; ++r) {
      long p = (mbase + wave * 16 + kg * 4 + r) * CC + cc;
      IO<T>::st(xo, p, acc2[nc2][r] + bb + IO<T>::ld(xo, p));
    }
  }
}
__global__ __launch_bounds__(256) void mlp_kernel(
    const int* __restrict__ flag, const void* n2g, const void* n2b,
    const void* fc1_w, const void* fc1_b, const void* fc2_w, const void* fc2_b,
    void* xo) {
  __shared__ short xln[64 * 104];
  __shared__ short w1c[64 * 104];
  __shared__ short w2c[96 * 72];
  if (*flag)
    mlp_body<float>((const float*)n2g, (const float*)n2b, (const float*)fc1_w,
                    (const float*)fc1_b, (const float*)fc2_w,
                    (const float*)fc2_b, (float*)xo, xln, w1c, w2c);
  else
    mlp_body<bf16>((const bf16*)n2g, (const bf16*)n2b, (const bf16*)fc1_w,
                   (const bf16*)fc1_b, (const bf16*)fc2_w, (const bf16*)fc2_b,
                   (bf16*)xo, xln, w1c, w2c);
}

// ---------------------------------------------------------------------------
extern "C" void kernel_launch(void* const* d_in, const int* in_sizes, int n_in,
                              void* d_out, int out_size, void* d_ws, size_t ws_size,
                              hipStream_t stream) {
  (void)in_sizes; (void)n_in; (void)out_size; (void)ws_size;
  char* ws = (char*)d_ws;
  bf16* bufA = (bf16*)ws;                                   // MTOT*96 bf16 = 77 MB
  size_t offA = (size_t)MTOT * CC * 2;
  bf16* comb = (bf16*)(ws + offA);                          // 256*3*2401 bf16 = 3.7 MB
  size_t offC = offA + (size_t)256 * NHH * 2401 * 2;
  int* flag = (int*)(ws + offC);

  const int* rel_index = (const int*)d_in[2];

  detect_kernel<<<1, 256, 0, stream>>>((const unsigned short*)d_in[0], flag);
  combine_kernel<<<7203, 256, 0, stream>>>(flag, d_in[1], rel_index, d_in[9], comb);
  // 1. LN1 + shift + QKV + attention -> bufA
  qkv_attn_kernel<<<WTOT, 256, 0, stream>>>(flag, d_in[0], d_in[3], d_in[4],
                                            d_in[5], d_in[6], comb, bufA);
  // 2. proj + scatter + shortcut -> x1 parked in d_out
  proj_kernel<<<MTOT / 128, 256, 0, stream>>>(flag, bufA, d_in[7], d_in[8],
                                              d_out, d_in[0]);
  // 3. LN2 + MLP + residual, in-place on d_out
  mlp_kernel<<<MTOT / 64, 256, 0, stream>>>(flag, d_in[10], d_in[11], d_in[12],
                                            d_in[13], d_in[14], d_in[15], d_out);
}